// Round 2
// baseline (991.195 us; speedup 1.0000x reference)
//
#include <hip/hip_runtime.h>
#include <hip/hip_bf16.h>

typedef __attribute__((ext_vector_type(8))) short short8;
typedef __attribute__((ext_vector_type(4))) float floatx4;
typedef unsigned short u16;

#define T_SZ 609
#define K1V  4872   // valid K of flattened LSTM output (609*8)
#define K1P  4896   // padded to multiple of 32

static __device__ __forceinline__ u16 f2bf(float f) {
    union { float f; unsigned u; } a; a.f = f;
    unsigned r = a.u + 0x7FFF + ((a.u >> 16) & 1);   // round-to-nearest-even
    return (u16)(r >> 16);
}

// ==================== fp32 -> bf16 conversion (weights) ====================
__global__ __launch_bounds__(256) void cvt_kernel(const float* __restrict__ s,
                                                  u16* __restrict__ d, int n) {
    int i = (blockIdx.x * 256 + threadIdx.x) * 8;
    if (i < n) {
        float4 a = *(const float4*)(s + i);
        float4 b = *(const float4*)(s + i + 4);
        u16 o[8] = { f2bf(a.x), f2bf(a.y), f2bf(a.z), f2bf(a.w),
                     f2bf(b.x), f2bf(b.y), f2bf(b.z), f2bf(b.w) };
        *(uint4*)(d + i) = *(const uint4*)o;
    }
}

// ============================ LSTM (3 fused layers, fp32) ============================
// 1 lane = 1 gate (32 gates) of one batch row; 2 rows per wave, 8 rows per block.
__global__ __launch_bounds__(256) void lstm3_kernel(
    const float* __restrict__ x,
    const float* __restrict__ Wih1, const float* __restrict__ Whh1,
    const float* __restrict__ bih1, const float* __restrict__ bhh1,
    const float* __restrict__ Wih2, const float* __restrict__ Whh2,
    const float* __restrict__ bih2, const float* __restrict__ bhh2,
    const float* __restrict__ Wih3, const float* __restrict__ Whh3,
    const float* __restrict__ bih3, const float* __restrict__ bhh3,
    u16* __restrict__ A1)
{
    __shared__ float xs[8 * T_SZ * 5];   // 97,440 B
    const int tid = threadIdx.x;
    const int b0  = blockIdx.x * 8;

    // coalesced stage of this block's 8 rows of x (contiguous in global)
    const float* xg = x + (size_t)b0 * (T_SZ * 5);
    for (int i = tid; i < 8 * T_SZ * 5; i += 256) xs[i] = xg[i];

    // zero the K padding columns of A1 (ws is poisoned each launch)
    if (tid < 192) {
        int r = tid / 24, c = tid - r * 24;
        A1[(size_t)(b0 + r) * K1P + K1V + c] = 0;
    }

    const int lane = tid & 63;
    const int gi   = lane & 31;       // gate index 0..31 (i:0-7, f:8-15, g:16-23, o:24-31)
    const int base = lane & 32;       // 32-lane group base within wave
    const int rowl = ((tid >> 6) << 1) | (lane >> 5);   // local row 0..7
    const int bb   = b0 + rowl;
    const int gt   = gi >> 3;
    const int jj   = gi & 7;          // hidden unit this lane owns

    // per-lane weight rows (fp32, in registers)
    float wi1[5], wh1[8], wi2[8], wh2[8], wi3[8], wh3[8];
#pragma unroll
    for (int k = 0; k < 5; ++k) wi1[k] = Wih1[gi * 5 + k];
#pragma unroll
    for (int k = 0; k < 8; ++k) {
        wh1[k] = Whh1[gi * 8 + k];
        wi2[k] = Wih2[gi * 8 + k];
        wh2[k] = Whh2[gi * 8 + k];
        wi3[k] = Wih3[gi * 8 + k];
        wh3[k] = Whh3[gi * 8 + k];
    }
    const float bs1 = bih1[gi] + bhh1[gi];
    const float bs2 = bih2[gi] + bhh2[gi];
    const float bs3 = bih3[gi] + bhh3[gi];

    // branchless activation: sigmoid for i/f/o, tanh (=2*sigm(2x)-1) for g
    const float am = (gt == 2) ? -2.f : -1.f;
    const float aa = (gt == 2) ?  2.f :  1.f;
    const float ab = (gt == 2) ? -1.f :  0.f;

    __syncthreads();

    float c1 = 0.f, c2 = 0.f, c3 = 0.f;
    float hh1[8], hh2[8], hh3[8];     // broadcast copies of each layer's h (prev step)
#pragma unroll
    for (int k = 0; k < 8; ++k) { hh1[k] = 0.f; hh2[k] = 0.f; hh3[k] = 0.f; }

    const float* xr = &xs[rowl * (T_SZ * 5)];
    u16* outp = A1 + (size_t)bb * K1P;

    for (int t = 0; t < T_SZ; ++t) {
        // -------- layer 1 --------
        float acc = bs1;
#pragma unroll
        for (int k = 0; k < 5; ++k) acc = __builtin_fmaf(wi1[k], xr[t * 5 + k], acc);
#pragma unroll
        for (int k = 0; k < 8; ++k) acc = __builtin_fmaf(wh1[k], hh1[k], acc);
        float e = __expf(am * acc);
        float v = __builtin_fmaf(aa, __fdividef(1.f, 1.f + e), ab);
        float vi = __shfl(v, base + jj,      64);
        float vf = __shfl(v, base + 8 + jj,  64);
        float vg = __shfl(v, base + 16 + jj, 64);
        float vo = __shfl(v, base + 24 + jj, 64);
        c1 = __builtin_fmaf(vf, c1, vi * vg);
        float ec = __expf(-2.f * __builtin_fabsf(c1));
        float th = (1.f - ec) * __fdividef(1.f, 1.f + ec);
        float h1 = vo * __builtin_copysignf(th, c1);
#pragma unroll
        for (int k = 0; k < 8; ++k) hh1[k] = __shfl(h1, base + k, 64);

        // -------- layer 2 --------
        acc = bs2;
#pragma unroll
        for (int k = 0; k < 8; ++k) acc = __builtin_fmaf(wi2[k], hh1[k], acc);
#pragma unroll
        for (int k = 0; k < 8; ++k) acc = __builtin_fmaf(wh2[k], hh2[k], acc);
        e = __expf(am * acc);
        v = __builtin_fmaf(aa, __fdividef(1.f, 1.f + e), ab);
        vi = __shfl(v, base + jj,      64);
        vf = __shfl(v, base + 8 + jj,  64);
        vg = __shfl(v, base + 16 + jj, 64);
        vo = __shfl(v, base + 24 + jj, 64);
        c2 = __builtin_fmaf(vf, c2, vi * vg);
        ec = __expf(-2.f * __builtin_fabsf(c2));
        th = (1.f - ec) * __fdividef(1.f, 1.f + ec);
        float h2 = vo * __builtin_copysignf(th, c2);
#pragma unroll
        for (int k = 0; k < 8; ++k) hh2[k] = __shfl(h2, base + k, 64);

        // -------- layer 3 --------
        acc = bs3;
#pragma unroll
        for (int k = 0; k < 8; ++k) acc = __builtin_fmaf(wi3[k], hh2[k], acc);
#pragma unroll
        for (int k = 0; k < 8; ++k) acc = __builtin_fmaf(wh3[k], hh3[k], acc);
        e = __expf(am * acc);
        v = __builtin_fmaf(aa, __fdividef(1.f, 1.f + e), ab);
        vi = __shfl(v, base + jj,      64);
        vf = __shfl(v, base + 8 + jj,  64);
        vg = __shfl(v, base + 16 + jj, 64);
        vo = __shfl(v, base + 24 + jj, 64);
        c3 = __builtin_fmaf(vf, c3, vi * vg);
        ec = __expf(-2.f * __builtin_fabsf(c3));
        th = (1.f - ec) * __fdividef(1.f, 1.f + ec);
        float h3 = vo * __builtin_copysignf(th, c3);
#pragma unroll
        for (int k = 0; k < 8; ++k) hh3[k] = __shfl(h3, base + k, 64);

        if (gi < 8) outp[t * 8 + gi] = f2bf(h3);
    }
}

// ============================ bf16 NT GEMM + bias + ReLU ============================
// C[m][n] = act( sum_k A[m][k] * B[n][k] + bias[n] ), 16x16x32 bf16 MFMA.
// 256 threads, 2x2 waves. BK = 32. Bias fp32; output bf16 or fp32 (OUTF32).
template<int BM, int BN, bool RELU, bool NGUARD, bool KGUARD, bool OUTF32>
__global__ __launch_bounds__(256) void gemm_bt(
    const u16* __restrict__ A, int lda,
    const u16* __restrict__ B, int ldb,
    const float* __restrict__ bias,
    void* __restrict__ Cv, int ldc,
    int N, int Kloop, int Kvalid)
{
    constexpr int WM = BM / 2, WN = BN / 2;
    constexpr int TM = WM / 16, TN = WN / 16;
    constexpr int LS = 40;                      // 32 + 8 pad (16B-aligned rows, no conflicts)
    __shared__ u16 As[BM * LS];
    __shared__ u16 Bs[BN * LS];

    const int tid = threadIdx.x;
    const int bm  = blockIdx.y * BM;
    const int bn  = blockIdx.x * BN;
    const int l   = tid & 63, w = tid >> 6;
    const int wr  = w >> 1, wc = w & 1;
    const int lr  = l & 15, q = l >> 4;

    floatx4 acc[TM][TN];
#pragma unroll
    for (int i = 0; i < TM; ++i)
#pragma unroll
        for (int j = 0; j < TN; ++j) acc[i][j] = (floatx4){0.f, 0.f, 0.f, 0.f};

    for (int k0 = 0; k0 < Kloop; k0 += 32) {
#pragma unroll
        for (int ci = tid; ci < BM * 4; ci += 256) {
            int r = ci >> 2, c = (ci & 3) << 3;
            uint4 v = *(const uint4*)&A[(size_t)(bm + r) * lda + k0 + c];
            *(uint4*)&As[r * LS + c] = v;
        }
#pragma unroll
        for (int ci = tid; ci < BN * 4; ci += 256) {
            int r = ci >> 2, c = (ci & 3) << 3;
            uint4 v = make_uint4(0u, 0u, 0u, 0u);
            bool ok = true;
            if (NGUARD) ok = (bn + r) < N;
            if (KGUARD) ok = ok && ((k0 + c + 8) <= Kvalid);
            if (ok) v = *(const uint4*)&B[(size_t)(bn + r) * ldb + k0 + c];
            *(uint4*)&Bs[r * LS + c] = v;
        }
        __syncthreads();

        short8 fa[TM], fb[TN];
#pragma unroll
        for (int i = 0; i < TM; ++i)
            fa[i] = *(const short8*)&As[(wr * WM + i * 16 + lr) * LS + q * 8];
#pragma unroll
        for (int j = 0; j < TN; ++j)
            fb[j] = *(const short8*)&Bs[(wc * WN + j * 16 + lr) * LS + q * 8];
#pragma unroll
        for (int i = 0; i < TM; ++i)
#pragma unroll
            for (int j = 0; j < TN; ++j)
                acc[i][j] = __builtin_amdgcn_mfma_f32_16x16x32_bf16(fa[i], fb[j], acc[i][j], 0, 0, 0);
        __syncthreads();
    }

    // epilogue: C/D layout col = lane&15, row = (lane>>4)*4 + reg  [m89/m91]
#pragma unroll
    for (int j = 0; j < TN; ++j) {
        int n = bn + wc * WN + j * 16 + lr;
        bool nok = (!NGUARD) || (n < N);
        float bv = nok ? bias[nok ? n : 0] : 0.f;
#pragma unroll
        for (int i = 0; i < TM; ++i) {
            int m0r = bm + wr * WM + i * 16 + q * 4;
#pragma unroll
            for (int r = 0; r < 4; ++r) {
                float vv = acc[i][j][r] + bv;
                if (RELU) vv = fmaxf(vv, 0.f);
                if (nok) {
                    size_t idx = (size_t)(m0r + r) * ldc + n;
                    if (OUTF32) ((float*)Cv)[idx] = vv;
                    else        ((u16*)Cv)[idx] = f2bf(vv);
                }
            }
        }
    }
}

// ============================ launch ============================
extern "C" void kernel_launch(void* const* d_in, const int* in_sizes, int n_in,
                              void* d_out, int out_size, void* d_ws, size_t ws_size,
                              hipStream_t stream)
{
    const float* x    = (const float*)d_in[0];
    const float* Wih1 = (const float*)d_in[1];
    const float* Whh1 = (const float*)d_in[2];
    const float* bih1 = (const float*)d_in[3];
    const float* bhh1 = (const float*)d_in[4];
    const float* Wih2 = (const float*)d_in[5];
    const float* Whh2 = (const float*)d_in[6];
    const float* bih2 = (const float*)d_in[7];
    const float* bhh2 = (const float*)d_in[8];
    const float* Wih3 = (const float*)d_in[9];
    const float* Whh3 = (const float*)d_in[10];
    const float* bih3 = (const float*)d_in[11];
    const float* bhh3 = (const float*)d_in[12];
    const float* W1 = (const float*)d_in[13];
    const float* b1 = (const float*)d_in[14];
    const float* W2 = (const float*)d_in[15];
    const float* b2 = (const float*)d_in[16];
    const float* W3 = (const float*)d_in[17];
    const float* b3 = (const float*)d_in[18];

    // ws layout (bf16 elements): A1[2048][4896], A2[2048][4096], A3[2048][1024],
    // W1b[4096*4872], W2b[1024*4096], W3b[609*1024]  (~86.4 MB total, all 16B-aligned)
    u16* A1  = (u16*)d_ws;
    u16* A2  = A1 + (size_t)2048 * K1P;
    u16* A3  = A2 + (size_t)2048 * 4096;
    u16* W1b = A3 + (size_t)2048 * 1024;
    u16* W2b = W1b + (size_t)4096 * K1V;
    u16* W3b = W2b + (size_t)1024 * 4096;

    // weight conversions fp32 -> bf16 (counts all divisible by 8)
    cvt_kernel<<<9744, 256, 0, stream>>>(W1, W1b, 4096 * K1V);
    cvt_kernel<<<2048, 256, 0, stream>>>(W2, W2b, 1024 * 4096);
    cvt_kernel<<<305, 256, 0, stream>>>(W3, W3b, T_SZ * 1024);

    lstm3_kernel<<<256, 256, 0, stream>>>(x, Wih1, Whh1, bih1, bhh1,
                                          Wih2, Whh2, bih2, bhh2,
                                          Wih3, Whh3, bih3, bhh3, A1);

    // L1: [2048,4896(4872)] x W1[4096,4872] -> relu -> A2 [2048,4096]  (bf16 out)
    gemm_bt<128, 128, true, false, true, false><<<dim3(32, 16), 256, 0, stream>>>(
        A1, K1P, W1b, K1V, b1, A2, 4096, 4096, K1P, K1V);

    // L2: [2048,4096] x W2[1024,4096] -> relu -> A3 [2048,1024]  (bf16 out)
    gemm_bt<64, 128, true, false, false, false><<<dim3(8, 32), 256, 0, stream>>>(
        A2, 4096, W2b, 4096, b2, A3, 1024, 1024, 4096, 4096);

    // L3: [2048,1024] x W3[609,1024] -> d_out [2048,609]  (fp32 out)
    gemm_bt<64, 128, false, true, false, true><<<dim3(5, 32), 256, 0, stream>>>(
        A3, 1024, W3b, 1024, b3, d_out, T_SZ, T_SZ, 1024, 1024);
}

// Round 3
// 765.172 us; speedup vs baseline: 1.2954x; 1.2954x over previous
//
#include <hip/hip_runtime.h>
#include <hip/hip_bf16.h>

typedef __attribute__((ext_vector_type(8))) short short8;
typedef __attribute__((ext_vector_type(4))) float floatx4;
typedef unsigned short u16;

#define T_SZ 609
#define K1V  4872   // valid K of flattened LSTM output (609*8)
#define K1P  4896   // padded to multiple of 32
#define N3P  640    // W3 rows padded (609 -> 640)

static __device__ __forceinline__ u16 f2bf(float f) {
    union { float f; unsigned u; } a; a.f = f;
    unsigned r = a.u + 0x7FFF + ((a.u >> 16) & 1);   // round-to-nearest-even
    return (u16)(r >> 16);
}

// async global->LDS, 16B per lane; LDS dest = wave-uniform base + lane*16
static __device__ __forceinline__ void gload_lds16(const u16* g, u16* l) {
    __builtin_amdgcn_global_load_lds(
        (const __attribute__((address_space(1))) void*)g,
        (__attribute__((address_space(3))) void*)l, 16, 0, 0);
}

// ==================== fp32 -> bf16 conversion (plain) ====================
__global__ __launch_bounds__(256) void cvt_kernel(const float* __restrict__ s,
                                                  u16* __restrict__ d, int n) {
    int i = (blockIdx.x * 256 + threadIdx.x) * 8;
    if (i < n) {
        float4 a = *(const float4*)(s + i);
        float4 b = *(const float4*)(s + i + 4);
        u16 o[8] = { f2bf(a.x), f2bf(a.y), f2bf(a.z), f2bf(a.w),
                     f2bf(b.x), f2bf(b.y), f2bf(b.z), f2bf(b.w) };
        *(uint4*)(d + i) = *(const uint4*)o;
    }
}

// ============== fp32 -> bf16 with row/col zero padding ==============
// src [R][K] -> dst [Rp][Kp]; pad region zero-filled. Grid covers Rp*Kp/8 chunks.
__global__ __launch_bounds__(256) void cvt_pad_kernel(const float* __restrict__ s,
                                                      u16* __restrict__ d,
                                                      int R, int K, int Kp) {
    int chunk = blockIdx.x * 256 + threadIdx.x;
    int cpr = Kp >> 3;
    int r = chunk / cpr;
    int c = (chunk - r * cpr) << 3;
    u16 o[8] = {0, 0, 0, 0, 0, 0, 0, 0};
    if (r < R && c < K) {
        const float* p = s + (size_t)r * K + c;
        float4 a = *(const float4*)p;
        float4 b = *(const float4*)(p + 4);
        o[0] = f2bf(a.x); o[1] = f2bf(a.y); o[2] = f2bf(a.z); o[3] = f2bf(a.w);
        o[4] = f2bf(b.x); o[5] = f2bf(b.y); o[6] = f2bf(b.z); o[7] = f2bf(b.w);
    }
    *(uint4*)&d[(size_t)r * Kp + c] = *(const uint4*)o;
}

// ============================ LSTM (3 fused layers, fp32) ============================
// 1 lane = 1 gate (32 gates) of one batch row; 2 rows/wave, 8 rows/block, 256 blocks.
// The 3 layers are software-pipelined: iteration t computes L3[t-2], L2[t-1], L1[t]
// (mutually independent -> 3 interleaved dependency chains per lane).
__global__ __launch_bounds__(256) void lstm3_kernel(
    const float* __restrict__ x,
    const float* __restrict__ Wih1, const float* __restrict__ Whh1,
    const float* __restrict__ bih1, const float* __restrict__ bhh1,
    const float* __restrict__ Wih2, const float* __restrict__ Whh2,
    const float* __restrict__ bih2, const float* __restrict__ bhh2,
    const float* __restrict__ Wih3, const float* __restrict__ Whh3,
    const float* __restrict__ bih3, const float* __restrict__ bhh3,
    u16* __restrict__ A1)
{
    __shared__ float xs[8 * T_SZ * 5];   // 97,440 B
    const int tid = threadIdx.x;
    const int b0  = blockIdx.x * 8;

    const float* xg = x + (size_t)b0 * (T_SZ * 5);
    for (int i = tid; i < 8 * T_SZ * 5; i += 256) xs[i] = xg[i];

    // zero the K padding columns of A1 (ws is poisoned each launch)
    if (tid < 192) {
        int r = tid / 24, c = tid - r * 24;
        A1[(size_t)(b0 + r) * K1P + K1V + c] = 0;
    }

    const int lane = tid & 63;
    const int gi   = lane & 31;       // gate index (i:0-7, f:8-15, g:16-23, o:24-31)
    const int base = lane & 32;       // 32-lane group base within wave
    const int rowl = ((tid >> 6) << 1) | (lane >> 5);
    const int bb   = b0 + rowl;
    const int gt   = gi >> 3;
    const int jj   = gi & 7;          // hidden unit this lane owns

    float wi1[5], wh1[8], wi2[8], wh2[8], wi3[8], wh3[8];
#pragma unroll
    for (int k = 0; k < 5; ++k) wi1[k] = Wih1[gi * 5 + k];
#pragma unroll
    for (int k = 0; k < 8; ++k) {
        wh1[k] = Whh1[gi * 8 + k];
        wi2[k] = Wih2[gi * 8 + k];
        wh2[k] = Whh2[gi * 8 + k];
        wi3[k] = Wih3[gi * 8 + k];
        wh3[k] = Whh3[gi * 8 + k];
    }
    const float bs1 = bih1[gi] + bhh1[gi];
    const float bs2 = bih2[gi] + bhh2[gi];
    const float bs3 = bih3[gi] + bhh3[gi];

    // branchless activation: sigmoid for i/f/o, tanh (=2*sigm(2x)-1) for g
    const float am = (gt == 2) ? -2.f : -1.f;
    const float aa = (gt == 2) ?  2.f :  1.f;
    const float ab = (gt == 2) ? -1.f :  0.f;

    __syncthreads();

    float c1 = 0.f, c2 = 0.f, c3 = 0.f;
    float hh1[8], hh2[8], hh3[8];
#pragma unroll
    for (int k = 0; k < 8; ++k) { hh1[k] = 0.f; hh2[k] = 0.f; hh3[k] = 0.f; }

    const float* xr = &xs[rowl * (T_SZ * 5)];
    u16* outp = A1 + (size_t)bb * K1P;

    // gate activation + cell update + h; returns h
    auto lstep = [&](float acc, float& c) -> float {
        float e = __expf(am * acc);
        float v = __builtin_fmaf(aa, __fdividef(1.f, 1.f + e), ab);
        float vi = __shfl(v, base + jj,      64);
        float vf = __shfl(v, base + 8 + jj,  64);
        float vg = __shfl(v, base + 16 + jj, 64);
        float vo = __shfl(v, base + 24 + jj, 64);
        c = __builtin_fmaf(vf, c, vi * vg);
        float ec = __expf(-2.f * __builtin_fabsf(c));
        float th = (1.f - ec) * __fdividef(1.f, 1.f + ec);
        return vo * __builtin_copysignf(th, c);
    };

    auto step1 = [&](int t) {
        float a = bs1, b = 0.f;
#pragma unroll
        for (int k = 0; k < 5; ++k) a = __builtin_fmaf(wi1[k], xr[t * 5 + k], a);
#pragma unroll
        for (int k = 0; k < 8; ++k) b = __builtin_fmaf(wh1[k], hh1[k], b);
        float h = lstep(a + b, c1);
#pragma unroll
        for (int k = 0; k < 8; ++k) hh1[k] = __shfl(h, base + k, 64);
    };
    auto step2 = [&]() {
        float a = bs2, b = 0.f;
#pragma unroll
        for (int k = 0; k < 8; ++k) a = __builtin_fmaf(wi2[k], hh1[k], a);
#pragma unroll
        for (int k = 0; k < 8; ++k) b = __builtin_fmaf(wh2[k], hh2[k], b);
        float h = lstep(a + b, c2);
#pragma unroll
        for (int k = 0; k < 8; ++k) hh2[k] = __shfl(h, base + k, 64);
    };
    auto step3 = [&](int t) {
        float a = bs3, b = 0.f;
#pragma unroll
        for (int k = 0; k < 8; ++k) a = __builtin_fmaf(wi3[k], hh2[k], a);
#pragma unroll
        for (int k = 0; k < 8; ++k) b = __builtin_fmaf(wh3[k], hh3[k], b);
        float h = lstep(a + b, c3);
#pragma unroll
        for (int k = 0; k < 8; ++k) hh3[k] = __shfl(h, base + k, 64);
        if (gi < 8) outp[t * 8 + gi] = f2bf(h);
    };

    // pipeline prologue
    step1(0);
    step2(); step1(1);
    // main loop: three independent chains per iteration
    for (int t = 2; t < T_SZ; ++t) {
        step3(t - 2);
        step2();
        step1(t);
    }
    // drain
    step3(T_SZ - 2);
    step2();
    step3(T_SZ - 1);
}

// ============================ bf16 NT GEMM + bias + (ReLU) ============================
// C[m][n] = act( sum_k A[m][k]*B[n][k] + bias[n] ). 16x16x32 bf16 MFMA, BK=32,
// m97-style async staging: global_load_lds dwordx4, unpadded LDS (row = 32 u16).
// All staging unguarded (inputs padded at source). Store-side N guard optional.
template<int BM, int BN, bool RELU, bool NGUARD, bool OUTF32>
__global__ __launch_bounds__(256) void gemm_bt(
    const u16* __restrict__ A, int lda,
    const u16* __restrict__ B, int ldb,
    const float* __restrict__ bias,
    void* __restrict__ Cv, int ldc, int N, int K)
{
    constexpr int WM = BM / 2, WN = BN / 2;
    constexpr int TM = WM / 16, TN = WN / 16;
    __shared__ u16 As[BM * 32];
    __shared__ u16 Bs[BN * 32];

    const int tid = threadIdx.x;
    const int bm  = blockIdx.y * BM;
    const int bn  = blockIdx.x * BN;
    const int l   = tid & 63, w = tid >> 6;
    const int wr  = w >> 1, wc = w & 1;
    const int lr  = l & 15, q = l >> 4;
    const int lrow = l >> 2;            // staging: lane -> row within 16-row group
    const int lcol = (l & 3) << 3;      // staging: lane -> 8-elem chunk

    floatx4 acc[TM][TN];
#pragma unroll
    for (int i = 0; i < TM; ++i)
#pragma unroll
        for (int j = 0; j < TN; ++j) acc[i][j] = (floatx4){0.f, 0.f, 0.f, 0.f};

    const u16* Ab = A + (size_t)bm * lda;
    const u16* Bb = B + (size_t)bn * ldb;

    for (int k0 = 0; k0 < K; k0 += 32) {
#pragma unroll
        for (int i = 0; i < BM / 64; ++i) {
            int r0 = w * (BM / 4) + i * 16;
            gload_lds16(Ab + (size_t)(r0 + lrow) * lda + k0 + lcol, &As[r0 * 32]);
        }
#pragma unroll
        for (int i = 0; i < BN / 64; ++i) {
            int r0 = w * (BN / 4) + i * 16;
            gload_lds16(Bb + (size_t)(r0 + lrow) * ldb + k0 + lcol, &Bs[r0 * 32]);
        }
        __syncthreads();

        short8 fa[TM], fb[TN];
#pragma unroll
        for (int i = 0; i < TM; ++i)
            fa[i] = *(const short8*)&As[(wr * WM + i * 16 + lr) * 32 + q * 8];
#pragma unroll
        for (int j = 0; j < TN; ++j)
            fb[j] = *(const short8*)&Bs[(wc * WN + j * 16 + lr) * 32 + q * 8];
#pragma unroll
        for (int i = 0; i < TM; ++i)
#pragma unroll
            for (int j = 0; j < TN; ++j)
                acc[i][j] = __builtin_amdgcn_mfma_f32_16x16x32_bf16(fa[i], fb[j], acc[i][j], 0, 0, 0);
        __syncthreads();
    }

    // epilogue: C/D layout col = lane&15, row = (lane>>4)*4 + reg  [m89/m91]
#pragma unroll
    for (int j = 0; j < TN; ++j) {
        int n = bn + wc * WN + j * 16 + lr;
        bool nok = (!NGUARD) || (n < N);
        float bv = nok ? bias[n] : 0.f;
#pragma unroll
        for (int i = 0; i < TM; ++i) {
            int m0r = bm + wr * WM + i * 16 + q * 4;
#pragma unroll
            for (int r = 0; r < 4; ++r) {
                float vv = acc[i][j][r] + bv;
                if (RELU) vv = fmaxf(vv, 0.f);
                if (nok) {
                    size_t idx = (size_t)(m0r + r) * ldc + n;
                    if (OUTF32) ((float*)Cv)[idx] = vv;
                    else        ((u16*)Cv)[idx] = f2bf(vv);
                }
            }
        }
    }
}

// ============================ launch ============================
extern "C" void kernel_launch(void* const* d_in, const int* in_sizes, int n_in,
                              void* d_out, int out_size, void* d_ws, size_t ws_size,
                              hipStream_t stream)
{
    const float* x    = (const float*)d_in[0];
    const float* Wih1 = (const float*)d_in[1];
    const float* Whh1 = (const float*)d_in[2];
    const float* bih1 = (const float*)d_in[3];
    const float* bhh1 = (const float*)d_in[4];
    const float* Wih2 = (const float*)d_in[5];
    const float* Whh2 = (const float*)d_in[6];
    const float* bih2 = (const float*)d_in[7];
    const float* bhh2 = (const float*)d_in[8];
    const float* Wih3 = (const float*)d_in[9];
    const float* Whh3 = (const float*)d_in[10];
    const float* bih3 = (const float*)d_in[11];
    const float* bhh3 = (const float*)d_in[12];
    const float* W1 = (const float*)d_in[13];
    const float* b1 = (const float*)d_in[14];
    const float* W2 = (const float*)d_in[15];
    const float* b2 = (const float*)d_in[16];
    const float* W3 = (const float*)d_in[17];
    const float* b3 = (const float*)d_in[18];

    // ws layout (bf16 elems): A1[2048][4896], A2[2048][4096], A3[2048][1024],
    // W1b[4096][4896] (K-padded), W2b[1024][4096], W3b[640][1024] (row-padded). ~91 MB.
    u16* A1  = (u16*)d_ws;
    u16* A2  = A1  + (size_t)2048 * K1P;
    u16* A3  = A2  + (size_t)2048 * 4096;
    u16* W1b = A3  + (size_t)2048 * 1024;
    u16* W2b = W1b + (size_t)4096 * K1P;
    u16* W3b = W2b + (size_t)1024 * 4096;

    // weight conversions fp32 -> bf16 (zero-padded where needed)
    cvt_pad_kernel<<<9792, 256, 0, stream>>>(W1, W1b, 4096, K1V, K1P);  // 4096*4896/8/256
    cvt_kernel<<<2048, 256, 0, stream>>>(W2, W2b, 1024 * 4096);
    cvt_pad_kernel<<<320, 256, 0, stream>>>(W3, W3b, T_SZ, 1024, 1024); // rows 609->640

    lstm3_kernel<<<256, 256, 0, stream>>>(x, Wih1, Whh1, bih1, bhh1,
                                          Wih2, Whh2, bih2, bhh2,
                                          Wih3, Whh3, bih3, bhh3, A1);

    // L1: [2048,4896] x W1b[4096,4896] -> relu -> A2 [2048,4096]  (bf16 out)
    gemm_bt<128, 128, true, false, false><<<dim3(32, 16), 256, 0, stream>>>(
        A1, K1P, W1b, K1P, b1, A2, 4096, 4096, K1P);

    // L2: [2048,4096] x W2b[1024,4096] -> relu -> A3 [2048,1024]  (bf16 out)
    gemm_bt<64, 128, true, false, false><<<dim3(8, 32), 256, 0, stream>>>(
        A2, 4096, W2b, 4096, b2, A3, 1024, 1024, 4096);

    // L3: [2048,1024] x W3b[640,1024] -> d_out [2048,609]  (fp32 out, store N-guard)
    gemm_bt<64, 128, false, true, true><<<dim3(5, 32), 256, 0, stream>>>(
        A3, 1024, W3b, 1024, b3, d_out, T_SZ, T_SZ, 1024);
}